// Round 3
// baseline (478.353 us; speedup 1.0000x reference)
//
#include <hip/hip_runtime.h>

// Problem dims
#define S_DIM 128
#define N_DIM 256
#define H_DIM 1024
#define E_DIM 512
#define V_DIM 32000
#define KE_DIM 1024
#define CIN 2560   // H + E + H  (A2 = [ctx | emb_x | h0])

typedef unsigned short u16;
typedef __bf16 bf16x8 __attribute__((ext_vector_type(8)));
typedef float  f32x4  __attribute__((ext_vector_type(4)));

union U16x8 { uint4 u; bf16x8 b; };

// f32 -> bf16 RNE
__device__ __forceinline__ unsigned f2bf(float x) {
  unsigned u = __float_as_uint(x);
  return (u + 0x7FFFu + ((u >> 16) & 1u)) >> 16;
}
__device__ __forceinline__ unsigned pk2(float a, float b) {
  return f2bf(a) | (f2bf(b) << 16);
}

__device__ __forceinline__ bf16x8 frag_from_global(const u16* p) {
  U16x8 t; t.u = *(const uint4*)p; return t.b;
}
__device__ __forceinline__ bf16x8 frag_from_lds(const u16* base, int byteoff) {
  U16x8 t; t.u = *(const uint4*)((const char*)base + byteoff); return t.b;
}

// XOR-swizzled LDS addressing: 16B chunks, chunk' = chunk ^ (row&7).
__device__ __forceinline__ int loff128(int row, int k) {  // 128-col tile (256 B/row)
  return row * 256 + ((((k >> 3) ^ (row & 7)) << 4) | ((k & 7) << 1));
}

__device__ __forceinline__ f32x4 mfma16(bf16x8 a, bf16x8 b, f32x4 c) {
  return __builtin_amdgcn_mfma_f32_16x16x32_bf16(a, b, c, 0, 0, 0);
}

// Manual grid barrier: plain launch, 256 blocks (one per CU -> co-residency
// guaranteed, no deadlock). Thread 0 arrives (device-scope add) and spins on
// an agent-scope relaxed load with s_sleep backoff; release/acquire fences
// make cross-XCD A2/h1b stores visible. Target is cumulative (256, 512).
__device__ __forceinline__ void grid_barrier(unsigned* cnt, unsigned target) {
  __syncthreads();
  if (threadIdx.x == 0) {
    __threadfence();   // release: flush this block's stores to device scope
    __hip_atomic_fetch_add(cnt, 1u, __ATOMIC_RELAXED, __HIP_MEMORY_SCOPE_AGENT);
    unsigned v;
    do {
      __builtin_amdgcn_s_sleep(2);
      v = __hip_atomic_load(cnt, __ATOMIC_RELAXED, __HIP_MEMORY_SCOPE_AGENT);
    } while (v < target);
    __threadfence();   // acquire: invalidate stale L1/L2 before remote reads
  }
  __syncthreads();
}

// Phase-overlaid LDS (union): max 32.9 KB
struct ShP1 { float acc[8][H_DIM]; float ml[16]; };           // 32832 B
struct ShP2 { u16 b[16 * 128]; float sg[256][17]; };          // 21504 B
struct ShP3 { u16 b[64 * 128]; };                             // 16384 B
union ShAll { ShP1 p1; ShP2 p2; ShP3 p3; };

// ---------------------------------------------------------------------------
// ONE plain-launch kernel, 256 blocks x 512 threads, 2 manual grid barriers.
// Phase 1: attention -> A2.  Phase 2: gates GEMM + fused LSTM -> h1/c1/h1b.
// Phase 3: fc GEMM -> pred.
// ---------------------------------------------------------------------------
__global__ __launch_bounds__(512) void kmega(
    const int*   __restrict__ inp,  const float* __restrict__ enc,
    const float* __restrict__ hid,  const float* __restrict__ cell0,
    const float* __restrict__ emb,  const float* __restrict__ Wen,
    const float* __restrict__ ben,  const float* __restrict__ Wih,
    const float* __restrict__ bih,  const float* __restrict__ Whh,
    const float* __restrict__ bhh,  const float* __restrict__ Wfc,
    const float* __restrict__ bfc,
    u16* __restrict__ A2, u16* __restrict__ h1b, unsigned* __restrict__ bar,
    float* __restrict__ pred, float* __restrict__ h1, float* __restrict__ c1)
{
  __shared__ ShAll sh;
  const int t    = threadIdx.x;
  const int wave = t >> 6, lane = t & 63;
  const int quad = lane >> 4, l15 = lane & 15;
  const int b    = blockIdx.x;

  // ========== Phase 1: online-softmax attention for n = b ==========
  // Wave w handles s-row PAIRS {2w+16j, 2w+16j+1}, j=0..7: two interleaved
  // shuffle-reduce chains hide ds_bpermute latency; one rescale per pair.
  {
    const int n = b;
    const float* Wrow = Wen + (KE_DIM - 1) * (2 * H_DIM);
    float4 we[4];
    #pragma unroll
    for (int ks = 0; ks < 4; ++ks)
      we[ks] = *(const float4*)(Wrow + H_DIM + ks * 256 + lane * 4);

    // hidden-part dot (s-invariant), redundant per wave
    float hd = 0.f;
    #pragma unroll
    for (int ks = 0; ks < 4; ++ks) {
      float4 wh = *(const float4*)(Wrow + ks * 256 + lane * 4);
      float4 hv = *(const float4*)(hid + n * H_DIM + ks * 256 + lane * 4);
      hd += wh.x * hv.x + wh.y * hv.y + wh.z * hv.z + wh.w * hv.w;
    }
    #pragma unroll
    for (int off = 32; off > 0; off >>= 1) hd += __shfl_xor(hd, off, 64);
    const float ebase = hd + ben[KE_DIM - 1];

    float m = -INFINITY, lsum = 0.f;
    float4 acc[4];
    #pragma unroll
    for (int ks = 0; ks < 4; ++ks) acc[ks] = make_float4(0.f, 0.f, 0.f, 0.f);

    const long rowstride  = (long)N_DIM * H_DIM;
    const long pairstride = 16L * rowstride;
    const float* p0 = enc + ((long)(2 * wave) * N_DIM + n) * H_DIM + lane * 4;
    const float* p1 = p0 + rowstride;
    float4 c0[4], c1v[4];
    #pragma unroll
    for (int ks = 0; ks < 4; ++ks) {
      c0[ks]  = *(const float4*)(p0 + ks * 256);
      c1v[ks] = *(const float4*)(p1 + ks * 256);
    }

    for (int j = 0; j < 8; ++j) {
      float4 n0[4], n1[4];
      const bool has = (j < 7);
      if (has) {   // prefetch next pair (128 B/lane in flight)
        #pragma unroll
        for (int ks = 0; ks < 4; ++ks) {
          n0[ks] = *(const float4*)(p0 + pairstride + ks * 256);
          n1[ks] = *(const float4*)(p1 + pairstride + ks * 256);
        }
      }
      float d0 = 0.f, d1 = 0.f;
      #pragma unroll
      for (int ks = 0; ks < 4; ++ks) {
        d0 += we[ks].x * c0[ks].x + we[ks].y * c0[ks].y +
              we[ks].z * c0[ks].z + we[ks].w * c0[ks].w;
        d1 += we[ks].x * c1v[ks].x + we[ks].y * c1v[ks].y +
              we[ks].z * c1v[ks].z + we[ks].w * c1v[ks].w;
      }
      #pragma unroll
      for (int off = 32; off > 0; off >>= 1) {   // two chains interleaved
        d0 += __shfl_xor(d0, off, 64);
        d1 += __shfl_xor(d1, off, 64);
      }
      const float e0 = fmaxf(ebase + d0, 0.f);
      const float e1 = fmaxf(ebase + d1, 0.f);
      const float nm = fmaxf(m, fmaxf(e0, e1));
      const float sc = __expf(m - nm);           // 0 on first iter (m=-inf)
      const float q0 = __expf(e0 - nm);
      const float q1 = __expf(e1 - nm);
      lsum = lsum * sc + q0 + q1;
      #pragma unroll
      for (int ks = 0; ks < 4; ++ks) {
        acc[ks].x = acc[ks].x * sc + q0 * c0[ks].x + q1 * c1v[ks].x;
        acc[ks].y = acc[ks].y * sc + q0 * c0[ks].y + q1 * c1v[ks].y;
        acc[ks].z = acc[ks].z * sc + q0 * c0[ks].z + q1 * c1v[ks].z;
        acc[ks].w = acc[ks].w * sc + q0 * c0[ks].w + q1 * c1v[ks].w;
      }
      m = nm;
      if (has) {
        #pragma unroll
        for (int ks = 0; ks < 4; ++ks) { c0[ks] = n0[ks]; c1v[ks] = n1[ks]; }
      }
      p0 += pairstride; p1 += pairstride;
    }

    // merge the 8 per-wave online-softmax states
    #pragma unroll
    for (int ks = 0; ks < 4; ++ks)
      *(float4*)&sh.p1.acc[wave][ks * 256 + lane * 4] = acc[ks];
    if (lane == 0) { sh.p1.ml[wave] = m; sh.p1.ml[8 + wave] = lsum; }
    __syncthreads();

    float M = sh.p1.ml[0];
    #pragma unroll
    for (int w = 1; w < 8; ++w) M = fmaxf(M, sh.p1.ml[w]);
    float f[8]; float L = 0.f;
    #pragma unroll
    for (int w = 0; w < 8; ++w) { f[w] = __expf(sh.p1.ml[w] - M); L += sh.p1.ml[8 + w] * f[w]; }
    const float invL = 1.0f / L;
    {
      const int e0 = t * 2;   // 512 threads x 2 elems = 1024 ctx cols
      float v0 = 0.f, v1 = 0.f;
      #pragma unroll
      for (int w = 0; w < 8; ++w) {
        v0 += sh.p1.acc[w][e0]     * f[w];
        v1 += sh.p1.acc[w][e0 + 1] * f[w];
      }
      *(unsigned*)&A2[(long)n * CIN + e0] = pk2(v0 * invL, v1 * invL);
    }
    // A2 tail: emb gather (cols 1024..1535) then h0 copy (cols 1536..2559)
    const int idx = inp[n];
    for (int j = t; j < E_DIM + H_DIM; j += 512) {
      float v = (j < E_DIM) ? emb[(long)idx * E_DIM + j]
                            : hid[n * H_DIM + (j - E_DIM)];
      A2[(long)n * CIN + H_DIM + j] = (u16)f2bf(v);
    }
  }

  // Phase-2 first weight tile: issue BEFORE the barrier (flies during spin)
  const int p2_br = t >> 5;          // 0..15  (B row within tile)
  const int p2_bk = (t & 31) * 4;    // 0..124 (k offset within tile)
  const int jbr = (p2_br >> 2) * H_DIM + b * 4 + (p2_br & 3);
  float4 wv = *(const float4*)(Wih + (long)jbr * 1536 + p2_bk);

  grid_barrier(bar, 256);

  // ========== Phase 2: gates GEMM + fused LSTM (8 waves, mt=2) ==========
  // Gate-interleaved BN=16: block b owns h = 4b..4b+3; B-rows are
  // j = g*1024 + 4b + q, so LSTM runs entirely in this block's epilogue.
  {
    f32x4 acc2[2];
    acc2[0] = (f32x4){0.f, 0.f, 0.f, 0.f};
    acc2[1] = (f32x4){0.f, 0.f, 0.f, 0.f};

    for (int kt = 0; kt < 20; ++kt) {
      const int k0 = kt * 128;
      uint2 pk; pk.x = pk2(wv.x, wv.y); pk.y = pk2(wv.z, wv.w);
      *(uint2*)((char*)sh.p2.b + loff128(p2_br, p2_bk)) = pk;
      if (kt + 1 < 20) {             // register prefetch of next B tile
        const int kn = k0 + 128 + p2_bk;
        const float* sn = (kn < 1536) ? (Wih + (long)jbr * 1536 + kn)
                                      : (Whh + (long)jbr * H_DIM + (kn - 1536));
        wv = *(const float4*)sn;
      }
      __syncthreads();
      #pragma unroll
      for (int kstep = 0; kstep < 4; ++kstep) {
        const int kl = kstep * 32 + quad * 8;
        const bf16x8 bfrag = frag_from_lds(sh.p2.b, loff128(l15, kl));
        #pragma unroll
        for (int mt = 0; mt < 2; ++mt) {
          const int row = wave * 32 + mt * 16 + l15;
          const bf16x8 afrag = frag_from_global(A2 + (long)row * CIN + k0 + kl);
          acc2[mt] = mfma16(afrag, bfrag, acc2[mt]);
        }
      }
      __syncthreads();
    }

    // stage biased gates into padded LDS
    {
      const int jj = (l15 >> 2) * H_DIM + b * 4 + (l15 & 3);
      const float bias = bih[jj] + bhh[jj];
      #pragma unroll
      for (int mt = 0; mt < 2; ++mt)
        #pragma unroll
        for (int r = 0; r < 4; ++r)
          sh.p2.sg[wave * 32 + mt * 16 + quad * 4 + r][l15] = acc2[mt][r] + bias;
    }
    __syncthreads();

    // fused LSTM pointwise (PyTorch gate order i,f,g,o)
    #pragma unroll
    for (int u = 0; u < 2; ++u) {
      const int id = t + u * 512;      // 1024 (n,q) pairs
      const int n2 = id >> 2, qg = id & 3, h = b * 4 + qg;
      const float gi = sh.p2.sg[n2][qg],      gf = sh.p2.sg[n2][4 + qg];
      const float gg = sh.p2.sg[n2][8 + qg],  go = sh.p2.sg[n2][12 + qg];
      const float si = 1.f / (1.f + __expf(-gi));
      const float sf = 1.f / (1.f + __expf(-gf));
      const float so = 1.f / (1.f + __expf(-go));
      const float tg = tanhf(gg);
      const float cv = sf * cell0[(long)n2 * H_DIM + h] + si * tg;
      const float hv = so * tanhf(cv);
      c1 [(long)n2 * H_DIM + h] = cv;
      h1 [(long)n2 * H_DIM + h] = hv;
      h1b[(long)n2 * H_DIM + h] = (u16)f2bf(hv);
    }
  }

  // Phase-3 first weight tile: issue BEFORE the barrier
  const int p3_br = t >> 3;          // 0..63
  const int p3_bk = (t & 7) * 16;    // 0,16,...,112
  float4 v3[4];
  {
    const float* bsrc0 = Wfc + (long)(b * 64 + p3_br) * H_DIM + p3_bk;
    #pragma unroll
    for (int i = 0; i < 4; ++i) v3[i] = *(const float4*)(bsrc0 + 4 * i);
  }

  grid_barrier(bar, 512);

  // ========== Phase 3: pred = h1 @ W_fc^T + b_fc (8 waves, mt=2, nt=4) =====
  // 500 col-tiles of 64 over 256 blocks (blocks 0..243 take 2).
  bool first = true;
  for (int tile = b; tile < V_DIM / 64; tile += 256) {
    const int j0 = tile * 64;
    const float* bsrc = Wfc + (long)(j0 + p3_br) * H_DIM + p3_bk;
    if (!first) {
      #pragma unroll
      for (int i = 0; i < 4; ++i) v3[i] = *(const float4*)(bsrc + 4 * i);
    }
    first = false;

    f32x4 acc3[2][4];
    #pragma unroll
    for (int mt = 0; mt < 2; ++mt)
      #pragma unroll
      for (int nt = 0; nt < 4; ++nt) acc3[mt][nt] = (f32x4){0.f, 0.f, 0.f, 0.f};

    for (int kt = 0; kt < 8; ++kt) {
      const int k0 = kt * 128;
      uint4 pa, pb;
      pa.x = pk2(v3[0].x, v3[0].y); pa.y = pk2(v3[0].z, v3[0].w);
      pa.z = pk2(v3[1].x, v3[1].y); pa.w = pk2(v3[1].z, v3[1].w);
      pb.x = pk2(v3[2].x, v3[2].y); pb.y = pk2(v3[2].z, v3[2].w);
      pb.z = pk2(v3[3].x, v3[3].y); pb.w = pk2(v3[3].z, v3[3].w);
      *(uint4*)((char*)sh.p3.b + loff128(p3_br, p3_bk)) = pa;
      *(uint4*)((char*)sh.p3.b + loff128(p3_br, p3_bk + 8)) = pb;
      if (kt + 1 < 8) {              // register prefetch of next W_fc tile
        const float* sn = bsrc + (k0 + 128);
        #pragma unroll
        for (int i = 0; i < 4; ++i) v3[i] = *(const float4*)(sn + 4 * i);
      }
      __syncthreads();
      #pragma unroll
      for (int kstep = 0; kstep < 4; ++kstep) {
        const int kl = kstep * 32 + quad * 8;
        bf16x8 bfrag[4], afrag[2];
        #pragma unroll
        for (int nt = 0; nt < 4; ++nt)
          bfrag[nt] = frag_from_lds(sh.p3.b, loff128(nt * 16 + l15, kl));
        #pragma unroll
        for (int mt = 0; mt < 2; ++mt)
          afrag[mt] = frag_from_global(h1b + (long)(wave * 32 + mt * 16 + l15) * H_DIM + k0 + kl);
        #pragma unroll
        for (int mt = 0; mt < 2; ++mt)
          #pragma unroll
          for (int nt = 0; nt < 4; ++nt)
            acc3[mt][nt] = mfma16(afrag[mt], bfrag[nt], acc3[mt][nt]);
      }
      __syncthreads();
    }

    #pragma unroll
    for (int nt = 0; nt < 4; ++nt) {
      const float bv = bfc[j0 + nt * 16 + l15];
      #pragma unroll
      for (int mt = 0; mt < 2; ++mt) {
        #pragma unroll
        for (int r = 0; r < 4; ++r) {
          const int row = wave * 32 + mt * 16 + quad * 4 + r;
          pred[(long)row * V_DIM + j0 + nt * 16 + l15] = acc3[mt][nt][r] + bv;
        }
      }
    }
  }
}

// ---------------------------------------------------------------------------
extern "C" void kernel_launch(void* const* d_in, const int* in_sizes, int n_in,
                              void* d_out, int out_size, void* d_ws, size_t ws_size,
                              hipStream_t stream) {
  const int*   inp  = (const int*)  d_in[0];
  const float* enc  = (const float*)d_in[1];
  const float* hid  = (const float*)d_in[2];
  const float* cel  = (const float*)d_in[3];
  const float* emb  = (const float*)d_in[4];
  const float* Wen  = (const float*)d_in[5];
  const float* ben  = (const float*)d_in[6];
  const float* Wih  = (const float*)d_in[7];
  const float* bih  = (const float*)d_in[8];
  const float* Whh  = (const float*)d_in[9];
  const float* bhh  = (const float*)d_in[10];
  const float* Wfc  = (const float*)d_in[11];
  const float* bfc  = (const float*)d_in[12];

  float* out  = (float*)d_out;
  float* pred = out;                              // [256, 32000]
  float* h1   = out + (long)N_DIM * V_DIM;        // [1, 256, 1024]
  float* c1   = h1 + (long)N_DIM * H_DIM;         // [1, 256, 1024]

  char* ws = (char*)d_ws;
  u16*      A2  = (u16*)ws;                       // 256*2560*2 = 1,310,720 B
  u16*      h1b = (u16*)(ws + 1310720);           // 256*1024*2 =   524,288 B
  unsigned* bar = (unsigned*)(ws + (2 << 20));    // barrier counter @ 2 MB

  hipMemsetAsync(bar, 0, 64, stream);             // zero barrier counter
  kmega<<<N_DIM, 512, 0, stream>>>(inp, enc, hid, cel, emb, Wen, ben,
                                   Wih, bih, Whh, bhh, Wfc, bfc,
                                   A2, h1b, bar, pred, h1, c1);
}